// Round 1
// 468.924 us; speedup vs baseline: 1.0756x; 1.0756x over previous
//
#include <hip/hip_runtime.h>

// Holt double-exponential smoothing, chunk-parallel decomposition.
//
// Recurrence (t>=2): s = 0.5*x + 0.5*(s_p + b_p); b = 0.5*(s - s_p) + 0.5*b_p
// is affine: state_t = A * state_{t-1} + (0.5 x, 0.25 x),
//   A = [[0.5, 0.5], [-0.25, 0.75]], |eigenvalues| = sqrt(0.5).
// Split each T=1024 sequence into C=16 chunks of L=64:
//   Phase A: per-chunk zero-init run (x held in registers) -> chunk-final state
//   Phase B: block-local serial scan over chunks with constant A^64
//   Phase C: exact sequential recurrence from corrected init, outputs -> regs
//   Phase D (NEW): 4-stage LDS transpose so every global store instruction
//            writes full 64B lines (lanes 0-3 = 4 consecutive float4s).
// Round-2 lesson: WRITE_SIZE was exactly 2x the output size. Per-lane 16B
// stores at 256B wave stride never complete a cache line within an
// instruction -> TCC emits 32B-granule HBM writes (2x amplification).
// Quirky init (faithful to reference): out[0]=0; out[1]=x[1] with NO state
// update; state entering t=2 is (0,0).

constexpr int T_STEPS = 1024;
constexpr int CHUNKS  = 16;            // chunks per sequence
constexpr int CLEN    = T_STEPS / CHUNKS;  // 64 steps per chunk
constexpr int CGROUPS = CLEN / 4;      // 16 float4 groups per chunk
constexpr int SEQ_PER_BLOCK = 256 / CHUNKS; // 16 sequences per block

// Compile-time A^64 in double precision.
struct Md { double a00, a01, a10, a11; };
constexpr Md apow(int n) {
    Md p{1.0, 0.0, 0.0, 1.0};
    const Md A{0.5, 0.5, -0.25, 0.75};
    for (int i = 0; i < n; ++i) {
        Md q{A.a00 * p.a00 + A.a01 * p.a10,
             A.a00 * p.a01 + A.a01 * p.a11,
             A.a10 * p.a00 + A.a11 * p.a10,
             A.a10 * p.a01 + A.a11 * p.a11};
        p = q;
    }
    return p;
}
constexpr Md P64 = apow(64);

// XOR swizzle on float4 index within a sequence's 64-f4 row: spreads the
// (chunk*4+j) pattern uniformly over LDS bank groups for both the strided
// producer writes and the contiguous consumer reads (8 accesses/bank = min).
__device__ __forceinline__ int swz(int f) { return f ^ ((f >> 3) & 3); }

__global__ __launch_bounds__(256)
void holt_chunked_kernel(const float* __restrict__ x, float* __restrict__ out) {
    const int tid   = threadIdx.x;
    const int chunk = tid & (CHUNKS - 1);
    const int sloc  = tid >> 4;  // local sequence index, 0..15
    const size_t seqBase = (size_t)blockIdx.x * SEQ_PER_BLOCK;
    const size_t seq  = seqBase + sloc;
    const size_t base = seq * T_STEPS + (size_t)chunk * CLEN;

    const float4* __restrict__ xv = reinterpret_cast<const float4*>(x + base);

    // Load the whole chunk into registers (16 float4 = 64 VGPRs).
    float4 v[CGROUPS];
#pragma unroll
    for (int g = 0; g < CGROUPS; ++g) v[g] = xv[g];

    float s = 0.0f, b = 0.0f;
    auto step = [&](float xval) {
        float sn = 0.5f * xval + 0.5f * (s + b);
        b = 0.5f * (sn - s) + 0.5f * b;
        s = sn;
    };

    // ---- Phase A: zero-init run, final state only ----
    if (chunk == 0) {
        // t=0: no update; t=1: no state update (quirky init); t=2,3: normal.
        step(v[0].z); step(v[0].w);
    } else {
        step(v[0].x); step(v[0].y); step(v[0].z); step(v[0].w);
    }
#pragma unroll
    for (int g = 1; g < CGROUPS; ++g) {
        step(v[g].x); step(v[g].y); step(v[g].z); step(v[g].w);
    }

    __shared__ float lS[256];
    __shared__ float lB[256];
    lS[tid] = s;
    lB[tid] = b;
    __syncthreads();

    // ---- Phase B: per-sequence scan over chunk states (16 threads active) ----
    if (tid < SEQ_PER_BLOCK) {
        const int o = tid * CHUNKS;
        const float p00 = (float)P64.a00, p01 = (float)P64.a01;
        const float p10 = (float)P64.a10, p11 = (float)P64.a11;
        float ts = lS[o], tb = lB[o];  // true state after chunk 0
        lS[o] = 0.0f; lB[o] = 0.0f;    // init for chunk 0
        for (int j = 1; j < CHUNKS; ++j) {
            float us = lS[o + j], ub = lB[o + j];
            lS[o + j] = ts;  lB[o + j] = tb;   // init state for chunk j
            float ns = us + p00 * ts + p01 * tb;
            float nb = ub + p10 * ts + p11 * tb;
            ts = ns; tb = nb;
        }
    }
    __syncthreads();

    // ---- Phase C: exact recurrence from corrected init; outputs -> v[] ----
    s = lS[sloc * CHUNKS + chunk];
    b = lB[sloc * CHUNKS + chunk];

    {
        float4 o0;
        if (chunk == 0) {
            o0.x = 0.0f;      // t=0
            o0.y = v[0].y;    // t=1 (state not updated)
            step(v[0].z); o0.z = s;
            step(v[0].w); o0.w = s;
        } else {
            step(v[0].x); o0.x = s;
            step(v[0].y); o0.y = s;
            step(v[0].z); o0.z = s;
            step(v[0].w); o0.w = s;
        }
        v[0] = o0;
    }
#pragma unroll
    for (int g = 1; g < CGROUPS; ++g) {
        float4 o;
        step(v[g].x); o.x = s;
        step(v[g].y); o.y = s;
        step(v[g].z); o.z = s;
        step(v[g].w); o.w = s;
        v[g] = o;
    }

    // ---- Phase D: LDS transpose -> full-line coalesced stores ----
    // Stage k covers float4 groups g = 4k..4k+3 of every chunk:
    //   16 seq x 16 chunk x 4 f4 = 1024 float4 = 16 KB.
    // Producer: thread (sloc, chunk) writes v[4k+j] at f = sloc*64+chunk*4+j.
    // Consumer: lane l of wave w, iter it: seqL = w*4+it, reads f = seqL*64+l,
    //   stores to out[seqG][chunk=(l>>2)&15][group 4k + (l&3)] -> lanes 0-3
    //   cover one full 64B line.
    __shared__ float4 xfer[SEQ_PER_BLOCK * CHUNKS * 4];  // 1024 float4 = 16 KB

    const int lane = tid & 63;
    const int wv   = tid >> 6;
    const int cc   = (lane >> 2) & 15;  // consumer chunk
    const int cj   = lane & 3;          // consumer f4-within-stage
    float4* __restrict__ ov4 = reinterpret_cast<float4*>(out);
    const int fbase = sloc * 64 + chunk * 4;

#pragma unroll
    for (int k = 0; k < 4; ++k) {
#pragma unroll
        for (int j = 0; j < 4; ++j) {
            xfer[swz(fbase + j)] = v[4 * k + j];
        }
        __syncthreads();
#pragma unroll
        for (int it = 0; it < 4; ++it) {
            const int seqL = wv * 4 + it;
            const float4 val = xfer[swz(seqL * 64 + lane)];
            const size_t idx = (seqBase + seqL) * (T_STEPS / 4)
                             + (size_t)cc * CGROUPS + k * 4 + cj;
            ov4[idx] = val;
        }
        __syncthreads();
    }
}

extern "C" void kernel_launch(void* const* d_in, const int* in_sizes, int n_in,
                              void* d_out, int out_size, void* d_ws, size_t ws_size,
                              hipStream_t stream) {
    const float* x = (const float*)d_in[0];
    float* out = (float*)d_out;

    const int nseq = in_sizes[0] / T_STEPS;          // 65536
    const int grid = nseq / SEQ_PER_BLOCK;           // 4096 blocks

    holt_chunked_kernel<<<grid, 256, 0, stream>>>(x, out);
}